// Round 8
// baseline (540.805 us; speedup 1.0000x reference)
//
#include <hip/hip_runtime.h>
#include <math.h>

#define BIN_SHIFT 8      // coarse bucket = dst >> 8 (256 nodes/bucket)
#define BIN_MAXB 512     // LDS array size (NB = ceil(N/256) = 391 for N=100000)
#define BIN_CHUNK 8192   // edges per block in coarse passes

// ---- bf16 helpers (RNE) ----
__device__ __forceinline__ float bf2f(unsigned short u) {
    union { unsigned int i; float f; } v;
    v.i = ((unsigned int)u) << 16;
    return v.f;
}
__device__ __forceinline__ unsigned short f2bf(float f) {
    union { float f; unsigned int i; } v;
    v.f = f;
    unsigned int r = v.i + 0x7FFF + ((v.i >> 16) & 1);
    return (unsigned short)(r >> 16);
}
__device__ __forceinline__ float lo_bf(unsigned int u) {
    union { unsigned int i; float f; } v;
    v.i = u << 16;
    return v.f;
}
__device__ __forceinline__ float hi_bf(unsigned int u) {
    union { unsigned int i; float f; } v;
    v.i = u & 0xFFFF0000u;
    return v.f;
}

// ---------------- coarse bucket histogram (LDS-local, ~391 global atomics/block)
__global__ __launch_bounds__(256) void k_ccount(const int* __restrict__ dst, int E,
                                                int* __restrict__ ccounts) {
    __shared__ int hist[BIN_MAXB];
    int t = threadIdx.x;
    int e0 = blockIdx.x * BIN_CHUNK;
    int eEnd = e0 + BIN_CHUNK;
    if (eEnd > E) eEnd = E;
    for (int i = t; i < BIN_MAXB; i += 256) hist[i] = 0;
    __syncthreads();
    for (int e = e0 + t; e < eEnd; e += 256)
        atomicAdd(&hist[dst[e] >> BIN_SHIFT], 1);
    __syncthreads();
    for (int i = t; i < BIN_MAXB; i += 256) {
        int h = hist[i];
        if (h > 0) atomicAdd(&ccounts[i], h);
    }
}

// ---------------- single-block scan of coarse counts -> coff, ccur
__global__ void k_cscan(const int* __restrict__ ccounts, int NB, int N,
                        int* __restrict__ coff, int* __restrict__ ccur,
                        int* __restrict__ offsets) {
    __shared__ int s[BIN_MAXB];
    int t = threadIdx.x;
    int v = (t < NB) ? ccounts[t] : 0;
    s[t] = v;
    __syncthreads();
    for (int off = 1; off < BIN_MAXB; off <<= 1) {
        int tmp = (t >= off) ? s[t - off] : 0;
        __syncthreads();
        s[t] += tmp;
        __syncthreads();
    }
    int excl = s[t] - v;
    if (t < NB) {
        coff[t] = excl;
        ccur[t] = excl;
    }
    if (t == NB - 1) {
        coff[NB] = s[t];      // total = E
        offsets[N] = s[t];
    }
}

// ---------------- pass A: coarse-bin edges into pairs[] as (src<<8)|(dst&255)
__global__ __launch_bounds__(256) void k_binA(const int* __restrict__ src,
                                              const int* __restrict__ dst, int E,
                                              int* __restrict__ ccur,
                                              unsigned int* __restrict__ pairs) {
    __shared__ int hist[BIN_MAXB];
    __shared__ int base[BIN_MAXB];
    int t = threadIdx.x;
    int e0 = blockIdx.x * BIN_CHUNK;
    int eEnd = e0 + BIN_CHUNK;
    if (eEnd > E) eEnd = E;
    for (int i = t; i < BIN_MAXB; i += 256) hist[i] = 0;
    __syncthreads();
    for (int e = e0 + t; e < eEnd; e += 256) {
        int d = dst[e];
        atomicAdd(&hist[d >> BIN_SHIFT], 1);
    }
    __syncthreads();
    for (int i = t; i < BIN_MAXB; i += 256) {
        int h = hist[i];
        base[i] = (h > 0) ? atomicAdd(&ccur[i], h) : 0;
        hist[i] = 0;  // reuse as local cursor
    }
    __syncthreads();
    for (int e = e0 + t; e < eEnd; e += 256) {
        int d = dst[e];
        int s = src[e];
        int b = d >> BIN_SHIFT;
        int lp = atomicAdd(&hist[b], 1);
        pairs[base[b] + lp] = ((unsigned int)s << BIN_SHIFT) | (unsigned int)(d & 255);
    }
}

// ---------------- pass B (merged): per-bucket fine count + scan + scatter.
__global__ __launch_bounds__(256) void k_binfine(const unsigned int* __restrict__ pairs,
                                                 const int* __restrict__ coff,
                                                 int N,
                                                 int* __restrict__ counts,
                                                 int* __restrict__ offsets,
                                                 int* __restrict__ sorted_src) {
    __shared__ int hist[256];
    __shared__ int scan[256];
    __shared__ int lcur[256];
    int b = blockIdx.x;
    int t = threadIdx.x;
    int beg = coff[b], end = coff[b + 1];
    int dbase = b << BIN_SHIFT;
    hist[t] = 0;
    __syncthreads();
    for (int e = beg + t; e < end; e += 256)
        atomicAdd(&hist[pairs[e] & 255u], 1);
    __syncthreads();
    int v = hist[t];
    scan[t] = v;
    __syncthreads();
    for (int off = 1; off < 256; off <<= 1) {
        int tmp = (t >= off) ? scan[t - off] : 0;
        __syncthreads();
        scan[t] += tmp;
        __syncthreads();
    }
    int excl = scan[t] - v;
    int node = dbase + t;
    if (node < N) {
        counts[node] = v;              // non-atomic: this block owns these nodes
        offsets[node] = beg + excl;
    }
    lcur[t] = beg + excl;
    __syncthreads();
    for (int e = beg + t; e < end; e += 256) {
        unsigned int pk = pairs[e];
        int pos = atomicAdd(&lcur[pk & 255u], 1);   // LDS atomic
        sorted_src[pos] = (int)(pk >> BIN_SHIFT);
    }
}

__global__ void k_dinv(const int* __restrict__ counts, int N, float* __restrict__ dinv) {
    int i = blockIdx.x * blockDim.x + threadIdx.x;
    if (i < N) dinv[i] = rsqrtf((float)counts[i] + 1.0f);
}

// xsc[i][f] = bf16(dinv[i] * x[i][f]); one thread per float4
__global__ void k_prep(const float* __restrict__ x, const float* __restrict__ dinv,
                       int N, unsigned short* __restrict__ xsc) {
    int i = blockIdx.x * blockDim.x + threadIdx.x;  // over N*16 float4s
    if (i >= N * 16) return;
    int node = i >> 4;
    float d = dinv[node];
    float4 v = ((const float4*)x)[i];
    ushort4 u;
    u.x = f2bf(v.x * d);
    u.y = f2bf(v.y * d);
    u.z = f2bf(v.z * d);
    u.w = f2bf(v.w * d);
    ((ushort4*)xsc)[i] = u;
}

// ---------------- aggregation over bf16, dinv-prescaled features
// Wave layout: g = lane>>3 picks one of 8 edges/iter, c = lane&7 picks an
// 8-feature octet (uint4 = 16 B). One gather instr covers 8 edge rows.
// 2x manual unroll -> >=2 gathers in flight per wave. Cross-group shfl reduce.
template <bool FINAL>
__global__ __launch_bounds__(256) void k_agg_bf(const unsigned short* __restrict__ fsc,
                                                const float* __restrict__ dinv,
                                                const int* __restrict__ offsets,
                                                const int* __restrict__ sorted_src,
                                                const float* __restrict__ b2,
                                                int N, float* __restrict__ out) {
    int wid = threadIdx.x >> 6;
    int lane = threadIdx.x & 63;
    int g = lane >> 3;   // edge slot 0..7
    int c = lane & 7;    // feature octet
    int i = blockIdx.x * 4 + wid;
    if (i >= N) return;
    int beg = offsets[i], end = offsets[i + 1];
    const unsigned short* fsc_c = fsc + (c << 3);

    float a0 = 0.f, a1 = 0.f, a2 = 0.f, a3 = 0.f;
    float a4 = 0.f, a5 = 0.f, a6 = 0.f, a7 = 0.f;

    int e = beg;
    // 2x unrolled: 16 edges per body, two independent gathers in flight
    for (; e + 15 < end; e += 16) {
        int s0 = sorted_src[e + g];
        int s1 = sorted_src[e + 8 + g];
        uint4 v0 = *(const uint4*)(fsc_c + ((unsigned)s0 << 6));
        uint4 v1 = *(const uint4*)(fsc_c + ((unsigned)s1 << 6));
        a0 += lo_bf(v0.x); a1 += hi_bf(v0.x);
        a2 += lo_bf(v0.y); a3 += hi_bf(v0.y);
        a4 += lo_bf(v0.z); a5 += hi_bf(v0.z);
        a6 += lo_bf(v0.w); a7 += hi_bf(v0.w);
        a0 += lo_bf(v1.x); a1 += hi_bf(v1.x);
        a2 += lo_bf(v1.y); a3 += hi_bf(v1.y);
        a4 += lo_bf(v1.z); a5 += hi_bf(v1.z);
        a6 += lo_bf(v1.w); a7 += hi_bf(v1.w);
    }
    for (; e + 7 < end; e += 8) {
        int s0 = sorted_src[e + g];
        uint4 v0 = *(const uint4*)(fsc_c + ((unsigned)s0 << 6));
        a0 += lo_bf(v0.x); a1 += hi_bf(v0.x);
        a2 += lo_bf(v0.y); a3 += hi_bf(v0.y);
        a4 += lo_bf(v0.z); a5 += hi_bf(v0.z);
        a6 += lo_bf(v0.w); a7 += hi_bf(v0.w);
    }
    int rem = end - e;
    if (rem > 0) {
        int idx = e + ((g < rem) ? g : 0);
        int s0 = sorted_src[idx];
        uint4 v0 = *(const uint4*)(fsc_c + ((unsigned)s0 << 6));
        if (g < rem) {
            a0 += lo_bf(v0.x); a1 += hi_bf(v0.x);
            a2 += lo_bf(v0.y); a3 += hi_bf(v0.y);
            a4 += lo_bf(v0.z); a5 += hi_bf(v0.z);
            a6 += lo_bf(v0.w); a7 += hi_bf(v0.w);
        }
    }
    // reduce across the 8 edge groups (lane bits 3,4,5)
#pragma unroll
    for (int m = 8; m <= 32; m <<= 1) {
        a0 += __shfl_xor(a0, m, 64);
        a1 += __shfl_xor(a1, m, 64);
        a2 += __shfl_xor(a2, m, 64);
        a3 += __shfl_xor(a3, m, 64);
        a4 += __shfl_xor(a4, m, 64);
        a5 += __shfl_xor(a5, m, 64);
        a6 += __shfl_xor(a6, m, 64);
        a7 += __shfl_xor(a7, m, 64);
    }
    // self-loop term (already dinv-scaled); identical on all lanes of a group
    {
        uint4 v = *(const uint4*)(fsc_c + ((unsigned)i << 6));
        a0 += lo_bf(v.x); a1 += hi_bf(v.x);
        a2 += lo_bf(v.y); a3 += hi_bf(v.y);
        a4 += lo_bf(v.z); a5 += hi_bf(v.z);
        a6 += lo_bf(v.w); a7 += hi_bf(v.w);
    }
    float di = dinv[i];
    if (!FINAL) {
        if (g == 0) {
            float* op = out + (size_t)i * 64 + (c << 3);
            *(float4*)(op + 0) = make_float4(a0 * di, a1 * di, a2 * di, a3 * di);
            *(float4*)(op + 4) = make_float4(a4 * di, a5 * di, a6 * di, a7 * di);
        }
    } else {
        const float* bp = b2 + (c << 3);
        float4 bA = *(const float4*)(bp + 0);
        float4 bB = *(const float4*)(bp + 4);
        float z0 = a0 * di + bA.x;
        float z1 = a1 * di + bA.y;
        float z2 = a2 * di + bA.z;
        float z3 = a3 * di + bA.w;
        float z4 = a4 * di + bB.x;
        float z5 = a5 * di + bB.y;
        float z6 = a6 * di + bB.z;
        float z7 = a7 * di + bB.w;
        float sq = z0 * z0 + z1 * z1 + z2 * z2 + z3 * z3 +
                   z4 * z4 + z5 * z5 + z6 * z6 + z7 * z7;
#pragma unroll
        for (int m = 1; m <= 4; m <<= 1) sq += __shfl_xor(sq, m, 64);
        float r = 1.0f / (sqrtf(sq) + 1e-12f);
        if (g == 0) {
            float* op = out + (size_t)i * 64 + (c << 3);
            *(float4*)(op + 0) = make_float4(z0 * r, z1 * r, z2 * r, z3 * r);
            *(float4*)(op + 4) = make_float4(z4 * r, z5 * r, z6 * r, z7 * r);
        }
    }
}

// ---------------- fused: gsc = bf16( dinv[i] * (relu(z1@W1 + b1) @ W2) )
// W1 staged as bf16 -> LDS ~50.5 KB -> 3 blocks/CU.
__global__ __launch_bounds__(256) void k_fused(const float* __restrict__ z1,
                                               const float* __restrict__ W1,
                                               const float* __restrict__ b1,
                                               const float* __restrict__ W2,
                                               const float* __restrict__ dinv,
                                               int N, unsigned short* __restrict__ gsc) {
    __shared__ unsigned short W1s[64 * 128];  // 16 KB (bf16)
    __shared__ unsigned short W2s[128 * 64];  // 16 KB (bf16)
    __shared__ float As[32][68];              // padded (aligned float4 rows, bank-spread)
    __shared__ unsigned short Hs[32][132];    // padded bf16 intermediate
    __shared__ float b1s[128];
    __shared__ float dl[32];

    int t = threadIdx.x;
    int r0blk = blockIdx.x * 32;

    for (int idx = t; idx < 2048; idx += 256) {
        float4 v = ((const float4*)W1)[idx];
        ushort4 u;
        u.x = f2bf(v.x); u.y = f2bf(v.y); u.z = f2bf(v.z); u.w = f2bf(v.w);
        ((ushort4*)W1s)[idx] = u;
    }
    for (int idx = t; idx < 2048; idx += 256) {
        float4 v = ((const float4*)W2)[idx];
        ushort4 u;
        u.x = f2bf(v.x); u.y = f2bf(v.y); u.z = f2bf(v.z); u.w = f2bf(v.w);
        ((ushort4*)W2s)[idx] = u;
    }
    if (t < 128) b1s[t] = b1[t];
    for (int idx = t; idx < 512; idx += 256) {
        int r = idx >> 4;
        int c4 = idx & 15;
        int row = r0blk + r;
        float4 v = (row < N) ? ((const float4*)z1)[(size_t)row * 16 + c4]
                             : make_float4(0.f, 0.f, 0.f, 0.f);
        *(float4*)&As[r][c4 * 4] = v;
    }
    if (t < 32) dl[t] = (r0blk + t < N) ? dinv[r0blk + t] : 0.f;
    __syncthreads();

    int rg = t >> 5;   // 0..7 (row group of 4)
    int cg = t & 31;   // 0..31
    int r0 = rg * 4;
    int c0 = cg * 4;   // stage-1 column base (128 cols)

    // ---- stage 1: H = relu(A @ W1 + b1), bf16 ----
    float acc[4][4];
#pragma unroll
    for (int j = 0; j < 4; j++)
#pragma unroll
        for (int q = 0; q < 4; q++) acc[j][q] = 0.f;
    for (int k = 0; k < 64; k++) {
        float a0 = As[r0 + 0][k];
        float a1 = As[r0 + 1][k];
        float a2 = As[r0 + 2][k];
        float a3 = As[r0 + 3][k];
        uint2 wu = *(const uint2*)&W1s[k * 128 + c0];
        float wx = lo_bf(wu.x), wy = hi_bf(wu.x);
        float wz = lo_bf(wu.y), ww = hi_bf(wu.y);
        acc[0][0] = fmaf(a0, wx, acc[0][0]); acc[0][1] = fmaf(a0, wy, acc[0][1]);
        acc[0][2] = fmaf(a0, wz, acc[0][2]); acc[0][3] = fmaf(a0, ww, acc[0][3]);
        acc[1][0] = fmaf(a1, wx, acc[1][0]); acc[1][1] = fmaf(a1, wy, acc[1][1]);
        acc[1][2] = fmaf(a1, wz, acc[1][2]); acc[1][3] = fmaf(a1, ww, acc[1][3]);
        acc[2][0] = fmaf(a2, wx, acc[2][0]); acc[2][1] = fmaf(a2, wy, acc[2][1]);
        acc[2][2] = fmaf(a2, wz, acc[2][2]); acc[2][3] = fmaf(a2, ww, acc[2][3]);
        acc[3][0] = fmaf(a3, wx, acc[3][0]); acc[3][1] = fmaf(a3, wy, acc[3][1]);
        acc[3][2] = fmaf(a3, wz, acc[3][2]); acc[3][3] = fmaf(a3, ww, acc[3][3]);
    }
#pragma unroll
    for (int j = 0; j < 4; j++) {
        ushort4 hu;
        hu.x = f2bf(fmaxf(acc[j][0] + b1s[c0 + 0], 0.f));
        hu.y = f2bf(fmaxf(acc[j][1] + b1s[c0 + 1], 0.f));
        hu.z = f2bf(fmaxf(acc[j][2] + b1s[c0 + 2], 0.f));
        hu.w = f2bf(fmaxf(acc[j][3] + b1s[c0 + 3], 0.f));
        *(ushort4*)&Hs[r0 + j][c0] = hu;
    }
    __syncthreads();

    // ---- stage 2: G = H @ W2, scale by dinv, emit bf16 ----
    float acc2[4][2];
#pragma unroll
    for (int j = 0; j < 4; j++) { acc2[j][0] = 0.f; acc2[j][1] = 0.f; }
    int c2 = cg * 2;  // stage-2 column base (64 cols)
    for (int k = 0; k < 128; k += 2) {
        ushort2 au0 = *(const ushort2*)&Hs[r0 + 0][k];
        ushort2 au1 = *(const ushort2*)&Hs[r0 + 1][k];
        ushort2 au2 = *(const ushort2*)&Hs[r0 + 2][k];
        ushort2 au3 = *(const ushort2*)&Hs[r0 + 3][k];
        ushort2 w0u = *(const ushort2*)&W2s[k * 64 + c2];
        ushort2 w1u = *(const ushort2*)&W2s[(k + 1) * 64 + c2];
        float wx0 = bf2f(w0u.x), wy0 = bf2f(w0u.y);
        float wx1 = bf2f(w1u.x), wy1 = bf2f(w1u.y);
        float a00 = bf2f(au0.x), a01 = bf2f(au0.y);
        float a10 = bf2f(au1.x), a11 = bf2f(au1.y);
        float a20 = bf2f(au2.x), a21 = bf2f(au2.y);
        float a30 = bf2f(au3.x), a31 = bf2f(au3.y);
        acc2[0][0] = fmaf(a00, wx0, fmaf(a01, wx1, acc2[0][0]));
        acc2[0][1] = fmaf(a00, wy0, fmaf(a01, wy1, acc2[0][1]));
        acc2[1][0] = fmaf(a10, wx0, fmaf(a11, wx1, acc2[1][0]));
        acc2[1][1] = fmaf(a10, wy0, fmaf(a11, wy1, acc2[1][1]));
        acc2[2][0] = fmaf(a20, wx0, fmaf(a21, wx1, acc2[2][0]));
        acc2[2][1] = fmaf(a20, wy0, fmaf(a21, wy1, acc2[2][1]));
        acc2[3][0] = fmaf(a30, wx0, fmaf(a31, wx1, acc2[3][0]));
        acc2[3][1] = fmaf(a30, wy0, fmaf(a31, wy1, acc2[3][1]));
    }
#pragma unroll
    for (int j = 0; j < 4; j++) {
        int row = r0blk + r0 + j;
        if (row < N) {
            float d = dl[r0 + j];
            ushort2 o;
            o.x = f2bf(acc2[j][0] * d);
            o.y = f2bf(acc2[j][1] * d);
            *(ushort2*)&gsc[(size_t)row * 64 + c2] = o;
        }
    }
}

// ---------------- decoder GEMM (64->256) fused with log_softmax
// One wave per 16 rows. F-tile transposed into wave-private LDS (broadcast
// ds_read_b128 in the loop). Wd read DIRECTLY from global per-k: it's 64 KB,
// L2-resident on every XCD -> frees 32 KB LDS -> 7 blocks/CU occupancy.
__global__ __launch_bounds__(256) void k_dec(const float* __restrict__ F,
                                             const float* __restrict__ Wd,
                                             const float* __restrict__ bd,
                                             int N, float* __restrict__ out) {
    __shared__ float bl[256];
    __shared__ float Ft[4][64][20];   // per-wave F^T tile [k][j], pad 16->20 (20 KB)
    int t = threadIdx.x;
    if (t < 256) bl[t] = bd[t];
    __syncthreads();
    int wid = t >> 6, lane = t & 63;
    int task = blockIdx.x * 4 + wid;   // one 16-row task per wave
    int r0 = task * 16;
    if (r0 >= N) return;

    // load 16 F rows (lane = k index), transpose-store into wave-private LDS
#pragma unroll
    for (int j4 = 0; j4 < 4; j4++) {
        float t0 = (r0 + j4 * 4 + 0 < N) ? F[(size_t)(r0 + j4 * 4 + 0) * 64 + lane] : 0.f;
        float t1 = (r0 + j4 * 4 + 1 < N) ? F[(size_t)(r0 + j4 * 4 + 1) * 64 + lane] : 0.f;
        float t2 = (r0 + j4 * 4 + 2 < N) ? F[(size_t)(r0 + j4 * 4 + 2) * 64 + lane] : 0.f;
        float t3 = (r0 + j4 * 4 + 3 < N) ? F[(size_t)(r0 + j4 * 4 + 3) * 64 + lane] : 0.f;
        *(float4*)&Ft[wid][lane][j4 * 4] = make_float4(t0, t1, t2, t3);
    }
    // no barrier needed: Ft slice is wave-private (compiler inserts lgkmcnt)

    float acc[16][4];
#pragma unroll
    for (int j = 0; j < 16; j++)
#pragma unroll
        for (int q = 0; q < 4; q++) acc[j][q] = 0.f;

    const float4* Wd4 = (const float4*)Wd;
    for (int k = 0; k < 64; k++) {
        float4 w4 = Wd4[k * 64 + lane];   // 16 B/lane, L2-broadcast hot (Wd = 64 KB)
        const float* fp = &Ft[wid][k][0];
        float4 f0 = *(const float4*)(fp + 0);
        float4 f1 = *(const float4*)(fp + 4);
        float4 f2 = *(const float4*)(fp + 8);
        float4 f3 = *(const float4*)(fp + 12);
        float fs[16] = {f0.x, f0.y, f0.z, f0.w, f1.x, f1.y, f1.z, f1.w,
                        f2.x, f2.y, f2.z, f2.w, f3.x, f3.y, f3.z, f3.w};
#pragma unroll
        for (int j = 0; j < 16; j++) {
            float fk = fs[j];
            acc[j][0] = fmaf(fk, w4.x, acc[j][0]);
            acc[j][1] = fmaf(fk, w4.y, acc[j][1]);
            acc[j][2] = fmaf(fk, w4.z, acc[j][2]);
            acc[j][3] = fmaf(fk, w4.w, acc[j][3]);
        }
    }

    float4 b4 = ((const float4*)bl)[lane];
#pragma unroll
    for (int j = 0; j < 16; j++) {
        int row = r0 + j;
        if (row >= N) break;
        float a0 = acc[j][0] + b4.x;
        float a1 = acc[j][1] + b4.y;
        float a2 = acc[j][2] + b4.z;
        float a3 = acc[j][3] + b4.w;
        float m = fmaxf(fmaxf(a0, a1), fmaxf(a2, a3));
#pragma unroll
        for (int mm = 32; mm >= 1; mm >>= 1) m = fmaxf(m, __shfl_xor(m, mm, 64));
        float s = __expf(a0 - m) + __expf(a1 - m) + __expf(a2 - m) + __expf(a3 - m);
#pragma unroll
        for (int mm = 32; mm >= 1; mm >>= 1) s += __shfl_xor(s, mm, 64);
        float lz = m + __logf(s);
        float4 o = make_float4(a0 - lz, a1 - lz, a2 - lz, a3 - lz);
        ((float4*)out)[(size_t)row * 64 + lane] = o;
    }
}

extern "C" void kernel_launch(void* const* d_in, const int* in_sizes, int n_in,
                              void* d_out, int out_size, void* d_ws, size_t ws_size,
                              hipStream_t stream) {
    const float* x = (const float*)d_in[0];
    const int* ei = (const int*)d_in[1];
    const float* W1 = (const float*)d_in[2];
    const float* b1 = (const float*)d_in[3];
    const float* W2 = (const float*)d_in[4];
    const float* b2 = (const float*)d_in[5];
    const float* Wd = (const float*)d_in[6];
    const float* bd = (const float*)d_in[7];
    int N = in_sizes[0] / 64;
    int E = in_sizes[1] / 2;
    const int* srcIdx = ei;
    const int* dstIdx = ei + E;
    int NB = (N + 255) >> BIN_SHIFT;  // coarse buckets

    char* w = (char*)d_ws;
    auto alloc = [&](size_t bytes) {
        void* p = (void*)w;
        w += (bytes + 255) & ~(size_t)255;
        return p;
    };
    int* counts = (int*)alloc((size_t)N * 4);
    int* offsets = (int*)alloc((size_t)(N + 1) * 4);
    int* ccounts = (int*)alloc((size_t)BIN_MAXB * 4);
    int* coff = (int*)alloc((size_t)(BIN_MAXB + 1) * 4);
    int* ccur = (int*)alloc((size_t)BIN_MAXB * 4);
    int* sorted_src = (int*)alloc((size_t)E * 4);
    float* dinv = (float*)alloc((size_t)N * 4);
    unsigned short* xsc = (unsigned short*)alloc((size_t)N * 64 * 2);
    unsigned short* gsc = (unsigned short*)alloc((size_t)N * 64 * 2);
    // z1 doubles as the pass-A pairs buffer (E*4 <= N*64*4 here); binfine
    // finishes before k_agg_bf<false> writes z1, same-stream ordering makes
    // the aliasing safe.
    size_t z1_bytes = (size_t)N * 64 * 4;
    size_t pairs_bytes = (size_t)E * 4;
    float* z1 = (float*)alloc(z1_bytes > pairs_bytes ? z1_bytes : pairs_bytes);
    unsigned int* pairs = (unsigned int*)z1;
    float* outLogp = (float*)d_out;
    float* outFinal = (float*)d_out + (size_t)N * 256;

    hipMemsetAsync(ccounts, 0, (size_t)BIN_MAXB * 4, stream);

    // coarse count -> scan -> bin -> per-bucket fine count/scan/scatter
    k_ccount<<<(E + BIN_CHUNK - 1) / BIN_CHUNK, 256, 0, stream>>>(dstIdx, E, ccounts);
    k_cscan<<<1, BIN_MAXB, 0, stream>>>(ccounts, NB, N, coff, ccur, offsets);
    k_binA<<<(E + BIN_CHUNK - 1) / BIN_CHUNK, 256, 0, stream>>>(srcIdx, dstIdx, E, ccur, pairs);
    k_binfine<<<NB, 256, 0, stream>>>(pairs, coff, N, counts, offsets, sorted_src);

    k_dinv<<<(N + 255) / 256, 256, 0, stream>>>(counts, N, dinv);
    k_prep<<<(N * 16 + 255) / 256, 256, 0, stream>>>(x, dinv, N, xsc);

    // layer 1: z1 = A_hat-weighted sum of xsc (already dinv-prescaled)
    k_agg_bf<false><<<(N + 3) / 4, 256, 0, stream>>>(xsc, dinv, offsets, sorted_src, nullptr, N, z1);

    // fused MLP: gsc = bf16(dinv .* (relu(z1@W1+b1) @ W2))
    k_fused<<<(N + 31) / 32, 256, 0, stream>>>(z1, W1, b1, W2, dinv, N, gsc);

    // layer 2 aggregation + bias + row-normalize -> final embeddings
    k_agg_bf<true><<<(N + 3) / 4, 256, 0, stream>>>(gsc, dinv, offsets, sorted_src, b2, N, outFinal);

    // decoder + log_softmax: one 16-row task per wave
    int nTasks = (N + 15) / 16;
    k_dec<<<(nTasks + 3) / 4, 256, 0, stream>>>(outFinal, Wd, bd, N, outLogp);
}

// Round 10
// 483.254 us; speedup vs baseline: 1.1191x; 1.1191x over previous
//
#include <hip/hip_runtime.h>
#include <math.h>

#define BIN_SHIFT 8      // coarse bucket = dst >> 8 (256 nodes/bucket)
#define BIN_MAXB 512     // LDS array size (NB = ceil(N/256) = 391 for N=100000)
#define BIN_CHUNK 8192   // edges per block in coarse passes

typedef __attribute__((ext_vector_type(8))) short bf16x8;
typedef __attribute__((ext_vector_type(4))) float f32x4;

// ---- bf16 helpers (RNE) ----
__device__ __forceinline__ float bf2f(unsigned short u) {
    union { unsigned int i; float f; } v;
    v.i = ((unsigned int)u) << 16;
    return v.f;
}
__device__ __forceinline__ unsigned short f2bf(float f) {
    union { float f; unsigned int i; } v;
    v.f = f;
    unsigned int r = v.i + 0x7FFF + ((v.i >> 16) & 1);
    return (unsigned short)(r >> 16);
}
__device__ __forceinline__ float lo_bf(unsigned int u) {
    union { unsigned int i; float f; } v;
    v.i = u << 16;
    return v.f;
}
__device__ __forceinline__ float hi_bf(unsigned int u) {
    union { unsigned int i; float f; } v;
    v.i = u & 0xFFFF0000u;
    return v.f;
}

// ---------------- coarse bucket histogram (LDS-local, ~391 global atomics/block)
__global__ __launch_bounds__(256) void k_ccount(const int* __restrict__ dst, int E,
                                                int* __restrict__ ccounts) {
    __shared__ int hist[BIN_MAXB];
    int t = threadIdx.x;
    int e0 = blockIdx.x * BIN_CHUNK;
    int eEnd = e0 + BIN_CHUNK;
    if (eEnd > E) eEnd = E;
    for (int i = t; i < BIN_MAXB; i += 256) hist[i] = 0;
    __syncthreads();
    for (int e = e0 + t; e < eEnd; e += 256)
        atomicAdd(&hist[dst[e] >> BIN_SHIFT], 1);
    __syncthreads();
    for (int i = t; i < BIN_MAXB; i += 256) {
        int h = hist[i];
        if (h > 0) atomicAdd(&ccounts[i], h);
    }
}

// ---------------- single-block scan of coarse counts -> coff, ccur
__global__ void k_cscan(const int* __restrict__ ccounts, int NB, int N,
                        int* __restrict__ coff, int* __restrict__ ccur,
                        int* __restrict__ offsets) {
    __shared__ int s[BIN_MAXB];
    int t = threadIdx.x;
    int v = (t < NB) ? ccounts[t] : 0;
    s[t] = v;
    __syncthreads();
    for (int off = 1; off < BIN_MAXB; off <<= 1) {
        int tmp = (t >= off) ? s[t - off] : 0;
        __syncthreads();
        s[t] += tmp;
        __syncthreads();
    }
    int excl = s[t] - v;
    if (t < NB) {
        coff[t] = excl;
        ccur[t] = excl;
    }
    if (t == NB - 1) {
        coff[NB] = s[t];      // total = E
        offsets[N] = s[t];
    }
}

// ---------------- pass A: coarse-bin edges into pairs[] as (src<<8)|(dst&255)
__global__ __launch_bounds__(256) void k_binA(const int* __restrict__ src,
                                              const int* __restrict__ dst, int E,
                                              int* __restrict__ ccur,
                                              unsigned int* __restrict__ pairs) {
    __shared__ int hist[BIN_MAXB];
    __shared__ int base[BIN_MAXB];
    int t = threadIdx.x;
    int e0 = blockIdx.x * BIN_CHUNK;
    int eEnd = e0 + BIN_CHUNK;
    if (eEnd > E) eEnd = E;
    for (int i = t; i < BIN_MAXB; i += 256) hist[i] = 0;
    __syncthreads();
    for (int e = e0 + t; e < eEnd; e += 256) {
        int d = dst[e];
        atomicAdd(&hist[d >> BIN_SHIFT], 1);
    }
    __syncthreads();
    for (int i = t; i < BIN_MAXB; i += 256) {
        int h = hist[i];
        base[i] = (h > 0) ? atomicAdd(&ccur[i], h) : 0;
        hist[i] = 0;  // reuse as local cursor
    }
    __syncthreads();
    for (int e = e0 + t; e < eEnd; e += 256) {
        int d = dst[e];
        int s = src[e];
        int b = d >> BIN_SHIFT;
        int lp = atomicAdd(&hist[b], 1);
        pairs[base[b] + lp] = ((unsigned int)s << BIN_SHIFT) | (unsigned int)(d & 255);
    }
}

// ---------------- pass B (merged): per-bucket fine count + scan + scatter.
__global__ __launch_bounds__(256) void k_binfine(const unsigned int* __restrict__ pairs,
                                                 const int* __restrict__ coff,
                                                 int N,
                                                 int* __restrict__ counts,
                                                 int* __restrict__ offsets,
                                                 int* __restrict__ sorted_src) {
    __shared__ int hist[256];
    __shared__ int scan[256];
    __shared__ int lcur[256];
    int b = blockIdx.x;
    int t = threadIdx.x;
    int beg = coff[b], end = coff[b + 1];
    int dbase = b << BIN_SHIFT;
    hist[t] = 0;
    __syncthreads();
    for (int e = beg + t; e < end; e += 256)
        atomicAdd(&hist[pairs[e] & 255u], 1);
    __syncthreads();
    int v = hist[t];
    scan[t] = v;
    __syncthreads();
    for (int off = 1; off < 256; off <<= 1) {
        int tmp = (t >= off) ? scan[t - off] : 0;
        __syncthreads();
        scan[t] += tmp;
        __syncthreads();
    }
    int excl = scan[t] - v;
    int node = dbase + t;
    if (node < N) {
        counts[node] = v;              // non-atomic: this block owns these nodes
        offsets[node] = beg + excl;
    }
    lcur[t] = beg + excl;
    __syncthreads();
    for (int e = beg + t; e < end; e += 256) {
        unsigned int pk = pairs[e];
        int pos = atomicAdd(&lcur[pk & 255u], 1);   // LDS atomic
        sorted_src[pos] = (int)(pk >> BIN_SHIFT);
    }
}

__global__ void k_dinv(const int* __restrict__ counts, int N, float* __restrict__ dinv) {
    int i = blockIdx.x * blockDim.x + threadIdx.x;
    if (i < N) dinv[i] = rsqrtf((float)counts[i] + 1.0f);
}

// xsc[i][f] = bf16(dinv[i] * x[i][f]); one thread per float4
__global__ void k_prep(const float* __restrict__ x, const float* __restrict__ dinv,
                       int N, unsigned short* __restrict__ xsc) {
    int i = blockIdx.x * blockDim.x + threadIdx.x;  // over N*16 float4s
    if (i >= N * 16) return;
    int node = i >> 4;
    float d = dinv[node];
    float4 v = ((const float4*)x)[i];
    ushort4 u;
    u.x = f2bf(v.x * d);
    u.y = f2bf(v.y * d);
    u.z = f2bf(v.z * d);
    u.w = f2bf(v.w * d);
    ((ushort4*)xsc)[i] = u;
}

// ---------------- aggregation over bf16, dinv-prescaled features
// Wave layout: g = lane>>3 picks one of 8 edges/iter, c = lane&7 picks an
// 8-feature octet (uint4 = 16 B). One gather instr covers 8 edge rows.
// FINAL: g==0 lanes write fp32 embeddings, g==1 lanes write a bf16 copy for
// the MFMA decoder (free: all groups hold the full value after the reduce).
template <bool FINAL>
__global__ __launch_bounds__(256) void k_agg_bf(const unsigned short* __restrict__ fsc,
                                                const float* __restrict__ dinv,
                                                const int* __restrict__ offsets,
                                                const int* __restrict__ sorted_src,
                                                const float* __restrict__ b2,
                                                int N, float* __restrict__ out,
                                                unsigned short* __restrict__ fbf) {
    int wid = threadIdx.x >> 6;
    int lane = threadIdx.x & 63;
    int g = lane >> 3;   // edge slot 0..7
    int c = lane & 7;    // feature octet
    int i = blockIdx.x * 4 + wid;
    if (i >= N) return;
    int beg = offsets[i], end = offsets[i + 1];
    const unsigned short* fsc_c = fsc + (c << 3);

    float a0 = 0.f, a1 = 0.f, a2 = 0.f, a3 = 0.f;
    float a4 = 0.f, a5 = 0.f, a6 = 0.f, a7 = 0.f;

    int e = beg;
    // 2x unrolled: 16 edges per body, two independent gathers in flight
    for (; e + 15 < end; e += 16) {
        int s0 = sorted_src[e + g];
        int s1 = sorted_src[e + 8 + g];
        uint4 v0 = *(const uint4*)(fsc_c + ((unsigned)s0 << 6));
        uint4 v1 = *(const uint4*)(fsc_c + ((unsigned)s1 << 6));
        a0 += lo_bf(v0.x); a1 += hi_bf(v0.x);
        a2 += lo_bf(v0.y); a3 += hi_bf(v0.y);
        a4 += lo_bf(v0.z); a5 += hi_bf(v0.z);
        a6 += lo_bf(v0.w); a7 += hi_bf(v0.w);
        a0 += lo_bf(v1.x); a1 += hi_bf(v1.x);
        a2 += lo_bf(v1.y); a3 += hi_bf(v1.y);
        a4 += lo_bf(v1.z); a5 += hi_bf(v1.z);
        a6 += lo_bf(v1.w); a7 += hi_bf(v1.w);
    }
    for (; e + 7 < end; e += 8) {
        int s0 = sorted_src[e + g];
        uint4 v0 = *(const uint4*)(fsc_c + ((unsigned)s0 << 6));
        a0 += lo_bf(v0.x); a1 += hi_bf(v0.x);
        a2 += lo_bf(v0.y); a3 += hi_bf(v0.y);
        a4 += lo_bf(v0.z); a5 += hi_bf(v0.z);
        a6 += lo_bf(v0.w); a7 += hi_bf(v0.w);
    }
    int rem = end - e;
    if (rem > 0) {
        int idx = e + ((g < rem) ? g : 0);
        int s0 = sorted_src[idx];
        uint4 v0 = *(const uint4*)(fsc_c + ((unsigned)s0 << 6));
        if (g < rem) {
            a0 += lo_bf(v0.x); a1 += hi_bf(v0.x);
            a2 += lo_bf(v0.y); a3 += hi_bf(v0.y);
            a4 += lo_bf(v0.z); a5 += hi_bf(v0.z);
            a6 += lo_bf(v0.w); a7 += hi_bf(v0.w);
        }
    }
    // reduce across the 8 edge groups (lane bits 3,4,5)
#pragma unroll
    for (int m = 8; m <= 32; m <<= 1) {
        a0 += __shfl_xor(a0, m, 64);
        a1 += __shfl_xor(a1, m, 64);
        a2 += __shfl_xor(a2, m, 64);
        a3 += __shfl_xor(a3, m, 64);
        a4 += __shfl_xor(a4, m, 64);
        a5 += __shfl_xor(a5, m, 64);
        a6 += __shfl_xor(a6, m, 64);
        a7 += __shfl_xor(a7, m, 64);
    }
    // self-loop term (already dinv-scaled); identical on all lanes of a group
    {
        uint4 v = *(const uint4*)(fsc_c + ((unsigned)i << 6));
        a0 += lo_bf(v.x); a1 += hi_bf(v.x);
        a2 += lo_bf(v.y); a3 += hi_bf(v.y);
        a4 += lo_bf(v.z); a5 += hi_bf(v.z);
        a6 += lo_bf(v.w); a7 += hi_bf(v.w);
    }
    float di = dinv[i];
    if (!FINAL) {
        if (g == 0) {
            float* op = out + (size_t)i * 64 + (c << 3);
            *(float4*)(op + 0) = make_float4(a0 * di, a1 * di, a2 * di, a3 * di);
            *(float4*)(op + 4) = make_float4(a4 * di, a5 * di, a6 * di, a7 * di);
        }
    } else {
        const float* bp = b2 + (c << 3);
        float4 bA = *(const float4*)(bp + 0);
        float4 bB = *(const float4*)(bp + 4);
        float z0 = a0 * di + bA.x;
        float z1 = a1 * di + bA.y;
        float z2 = a2 * di + bA.z;
        float z3 = a3 * di + bA.w;
        float z4 = a4 * di + bB.x;
        float z5 = a5 * di + bB.y;
        float z6 = a6 * di + bB.z;
        float z7 = a7 * di + bB.w;
        float sq = z0 * z0 + z1 * z1 + z2 * z2 + z3 * z3 +
                   z4 * z4 + z5 * z5 + z6 * z6 + z7 * z7;
#pragma unroll
        for (int m = 1; m <= 4; m <<= 1) sq += __shfl_xor(sq, m, 64);
        float r = 1.0f / (sqrtf(sq) + 1e-12f);
        if (g == 0) {
            float* op = out + (size_t)i * 64 + (c << 3);
            *(float4*)(op + 0) = make_float4(z0 * r, z1 * r, z2 * r, z3 * r);
            *(float4*)(op + 4) = make_float4(z4 * r, z5 * r, z6 * r, z7 * r);
        } else if (g == 1) {
            uint4 pk;
            pk.x = (unsigned)f2bf(z0 * r) | ((unsigned)f2bf(z1 * r) << 16);
            pk.y = (unsigned)f2bf(z2 * r) | ((unsigned)f2bf(z3 * r) << 16);
            pk.z = (unsigned)f2bf(z4 * r) | ((unsigned)f2bf(z5 * r) << 16);
            pk.w = (unsigned)f2bf(z6 * r) | ((unsigned)f2bf(z7 * r) << 16);
            *(uint4*)(fbf + (size_t)i * 64 + (c << 3)) = pk;
        }
    }
}

// ---------------- fused: gsc = bf16( dinv[i] * (relu(z1@W1 + b1) @ W2) )
// W1 staged as bf16 -> LDS ~50.5 KB -> 3 blocks/CU.
__global__ __launch_bounds__(256) void k_fused(const float* __restrict__ z1,
                                               const float* __restrict__ W1,
                                               const float* __restrict__ b1,
                                               const float* __restrict__ W2,
                                               const float* __restrict__ dinv,
                                               int N, unsigned short* __restrict__ gsc) {
    __shared__ unsigned short W1s[64 * 128];  // 16 KB (bf16)
    __shared__ unsigned short W2s[128 * 64];  // 16 KB (bf16)
    __shared__ float As[32][68];              // padded (aligned float4 rows, bank-spread)
    __shared__ unsigned short Hs[32][132];    // padded bf16 intermediate
    __shared__ float b1s[128];
    __shared__ float dl[32];

    int t = threadIdx.x;
    int r0blk = blockIdx.x * 32;

    for (int idx = t; idx < 2048; idx += 256) {
        float4 v = ((const float4*)W1)[idx];
        ushort4 u;
        u.x = f2bf(v.x); u.y = f2bf(v.y); u.z = f2bf(v.z); u.w = f2bf(v.w);
        ((ushort4*)W1s)[idx] = u;
    }
    for (int idx = t; idx < 2048; idx += 256) {
        float4 v = ((const float4*)W2)[idx];
        ushort4 u;
        u.x = f2bf(v.x); u.y = f2bf(v.y); u.z = f2bf(v.z); u.w = f2bf(v.w);
        ((ushort4*)W2s)[idx] = u;
    }
    if (t < 128) b1s[t] = b1[t];
    for (int idx = t; idx < 512; idx += 256) {
        int r = idx >> 4;
        int c4 = idx & 15;
        int row = r0blk + r;
        float4 v = (row < N) ? ((const float4*)z1)[(size_t)row * 16 + c4]
                             : make_float4(0.f, 0.f, 0.f, 0.f);
        *(float4*)&As[r][c4 * 4] = v;
    }
    if (t < 32) dl[t] = (r0blk + t < N) ? dinv[r0blk + t] : 0.f;
    __syncthreads();

    int rg = t >> 5;   // 0..7 (row group of 4)
    int cg = t & 31;   // 0..31
    int r0 = rg * 4;
    int c0 = cg * 4;   // stage-1 column base (128 cols)

    // ---- stage 1: H = relu(A @ W1 + b1), bf16 ----
    float acc[4][4];
#pragma unroll
    for (int j = 0; j < 4; j++)
#pragma unroll
        for (int q = 0; q < 4; q++) acc[j][q] = 0.f;
    for (int k = 0; k < 64; k++) {
        float a0 = As[r0 + 0][k];
        float a1 = As[r0 + 1][k];
        float a2 = As[r0 + 2][k];
        float a3 = As[r0 + 3][k];
        uint2 wu = *(const uint2*)&W1s[k * 128 + c0];
        float wx = lo_bf(wu.x), wy = hi_bf(wu.x);
        float wz = lo_bf(wu.y), ww = hi_bf(wu.y);
        acc[0][0] = fmaf(a0, wx, acc[0][0]); acc[0][1] = fmaf(a0, wy, acc[0][1]);
        acc[0][2] = fmaf(a0, wz, acc[0][2]); acc[0][3] = fmaf(a0, ww, acc[0][3]);
        acc[1][0] = fmaf(a1, wx, acc[1][0]); acc[1][1] = fmaf(a1, wy, acc[1][1]);
        acc[1][2] = fmaf(a1, wz, acc[1][2]); acc[1][3] = fmaf(a1, ww, acc[1][3]);
        acc[2][0] = fmaf(a2, wx, acc[2][0]); acc[2][1] = fmaf(a2, wy, acc[2][1]);
        acc[2][2] = fmaf(a2, wz, acc[2][2]); acc[2][3] = fmaf(a2, ww, acc[2][3]);
        acc[3][0] = fmaf(a3, wx, acc[3][0]); acc[3][1] = fmaf(a3, wy, acc[3][1]);
        acc[3][2] = fmaf(a3, wz, acc[3][2]); acc[3][3] = fmaf(a3, ww, acc[3][3]);
    }
#pragma unroll
    for (int j = 0; j < 4; j++) {
        ushort4 hu;
        hu.x = f2bf(fmaxf(acc[j][0] + b1s[c0 + 0], 0.f));
        hu.y = f2bf(fmaxf(acc[j][1] + b1s[c0 + 1], 0.f));
        hu.z = f2bf(fmaxf(acc[j][2] + b1s[c0 + 2], 0.f));
        hu.w = f2bf(fmaxf(acc[j][3] + b1s[c0 + 3], 0.f));
        *(ushort4*)&Hs[r0 + j][c0] = hu;
    }
    __syncthreads();

    // ---- stage 2: G = H @ W2, scale by dinv, emit bf16 ----
    float acc2[4][2];
#pragma unroll
    for (int j = 0; j < 4; j++) { acc2[j][0] = 0.f; acc2[j][1] = 0.f; }
    int c2 = cg * 2;  // stage-2 column base (64 cols)
    for (int k = 0; k < 128; k += 2) {
        ushort2 au0 = *(const ushort2*)&Hs[r0 + 0][k];
        ushort2 au1 = *(const ushort2*)&Hs[r0 + 1][k];
        ushort2 au2 = *(const ushort2*)&Hs[r0 + 2][k];
        ushort2 au3 = *(const ushort2*)&Hs[r0 + 3][k];
        ushort2 w0u = *(const ushort2*)&W2s[k * 64 + c2];
        ushort2 w1u = *(const ushort2*)&W2s[(k + 1) * 64 + c2];
        float wx0 = bf2f(w0u.x), wy0 = bf2f(w0u.y);
        float wx1 = bf2f(w1u.x), wy1 = bf2f(w1u.y);
        float a00 = bf2f(au0.x), a01 = bf2f(au0.y);
        float a10 = bf2f(au1.x), a11 = bf2f(au1.y);
        float a20 = bf2f(au2.x), a21 = bf2f(au2.y);
        float a30 = bf2f(au3.x), a31 = bf2f(au3.y);
        acc2[0][0] = fmaf(a00, wx0, fmaf(a01, wx1, acc2[0][0]));
        acc2[0][1] = fmaf(a00, wy0, fmaf(a01, wy1, acc2[0][1]));
        acc2[1][0] = fmaf(a10, wx0, fmaf(a11, wx1, acc2[1][0]));
        acc2[1][1] = fmaf(a10, wy0, fmaf(a11, wy1, acc2[1][1]));
        acc2[2][0] = fmaf(a20, wx0, fmaf(a21, wx1, acc2[2][0]));
        acc2[2][1] = fmaf(a20, wy0, fmaf(a21, wy1, acc2[2][1]));
        acc2[3][0] = fmaf(a30, wx0, fmaf(a31, wx1, acc2[3][0]));
        acc2[3][1] = fmaf(a30, wy0, fmaf(a31, wy1, acc2[3][1]));
    }
#pragma unroll
    for (int j = 0; j < 4; j++) {
        int row = r0blk + r0 + j;
        if (row < N) {
            float d = dl[r0 + j];
            ushort2 o;
            o.x = f2bf(acc2[j][0] * d);
            o.y = f2bf(acc2[j][1] * d);
            *(ushort2*)&gsc[(size_t)row * 64 + c2] = o;
        }
    }
}

// ---------------- decoder GEMM (64->256) via MFMA, fused log_softmax
// 4 waves/block; wave w owns cols w*64..w*64+63 as 4 col-tiles of 16.
// B-frags (Wd, bf16) live in REGISTERS, loaded once per block (Wd=64KB, L2-hot).
// Grid-stride over 16-row tasks: 2 A-frag loads (bf16 F copy) + 8 MFMAs +
// cross-wave softmax reduce through 512 B of LDS.
// Frag layouts (gfx950, HW-verified m89/m91): A row=lane&15,k=(lane>>4)*8+j;
// B col=lane&15, same k; D col=lane&15,row=(lane>>4)*4+r.
__global__ __launch_bounds__(256, 2) void k_dec(const unsigned short* __restrict__ Fbf,
                                                const float* __restrict__ Wd,
                                                const float* __restrict__ bd,
                                                int N, float* __restrict__ out) {
    __shared__ float redM[4][16];
    __shared__ float redS[4][16];
    int t = threadIdx.x;
    int w = t >> 6, lane = t & 63;
    int l15 = lane & 15, lhi = lane >> 4;
    int cbase = w * 64;

    // B fragments + bias, once per block
    bf16x8 B[4][2];
    float bb[4];
#pragma unroll
    for (int c = 0; c < 4; c++) {
        int col = cbase + c * 16 + l15;
        bb[c] = bd[col];
#pragma unroll
        for (int kh = 0; kh < 2; kh++) {
            bf16x8 bf;
#pragma unroll
            for (int j = 0; j < 8; j++) {
                int k = kh * 32 + lhi * 8 + j;
                bf[j] = (short)f2bf(Wd[k * 256 + col]);
            }
            B[c][kh] = bf;
        }
    }

    int nTasks = (N + 15) / 16;
    for (int task = blockIdx.x; task < nTasks; task += gridDim.x) {
        int r0 = task * 16;
        int rowA = r0 + l15;
        bf16x8 A0 = {};
        bf16x8 A1 = {};
        if (rowA < N) {
            A0 = *(const bf16x8*)(Fbf + (size_t)rowA * 64 + lhi * 8);
            A1 = *(const bf16x8*)(Fbf + (size_t)rowA * 64 + 32 + lhi * 8);
        }
        float z[4][4];  // [col-tile][r]
#pragma unroll
        for (int c = 0; c < 4; c++) {
            f32x4 acc = {0.f, 0.f, 0.f, 0.f};
            acc = __builtin_amdgcn_mfma_f32_16x16x32_bf16(A0, B[c][0], acc, 0, 0, 0);
            acc = __builtin_amdgcn_mfma_f32_16x16x32_bf16(A1, B[c][1], acc, 0, 0, 0);
#pragma unroll
            for (int r = 0; r < 4; r++) z[c][r] = acc[r] + bb[c];
        }
        // per-row max over this wave's 64 cols
        float M[4];
#pragma unroll
        for (int r = 0; r < 4; r++) {
            float m = fmaxf(fmaxf(z[0][r], z[1][r]), fmaxf(z[2][r], z[3][r]));
#pragma unroll
            for (int mm = 1; mm <= 8; mm <<= 1) m = fmaxf(m, __shfl_xor(m, mm, 64));
            M[r] = m;
        }
        if (l15 == 0) {
#pragma unroll
            for (int r = 0; r < 4; r++) redM[w][lhi * 4 + r] = M[r];
        }
        __syncthreads();
        float sr[4];
#pragma unroll
        for (int r = 0; r < 4; r++) {
            int rl = lhi * 4 + r;
            M[r] = fmaxf(fmaxf(redM[0][rl], redM[1][rl]), fmaxf(redM[2][rl], redM[3][rl]));
            float s = __expf(z[0][r] - M[r]) + __expf(z[1][r] - M[r]) +
                      __expf(z[2][r] - M[r]) + __expf(z[3][r] - M[r]);
#pragma unroll
            for (int mm = 1; mm <= 8; mm <<= 1) s += __shfl_xor(s, mm, 64);
            sr[r] = s;
        }
        if (l15 == 0) {
#pragma unroll
            for (int r = 0; r < 4; r++) redS[w][lhi * 4 + r] = sr[r];
        }
        __syncthreads();
#pragma unroll
        for (int r = 0; r < 4; r++) {
            int rl = lhi * 4 + r;
            int grow = r0 + rl;
            if (grow < N) {
                float s = redS[0][rl] + redS[1][rl] + redS[2][rl] + redS[3][rl];
                float lz = M[r] + __logf(s);
#pragma unroll
                for (int c = 0; c < 4; c++)
                    out[(size_t)grow * 256 + cbase + c * 16 + l15] = z[c][r] - lz;
            }
        }
        __syncthreads();  // protect redM/redS before next iteration's writes
    }
}

extern "C" void kernel_launch(void* const* d_in, const int* in_sizes, int n_in,
                              void* d_out, int out_size, void* d_ws, size_t ws_size,
                              hipStream_t stream) {
    const float* x = (const float*)d_in[0];
    const int* ei = (const int*)d_in[1];
    const float* W1 = (const float*)d_in[2];
    const float* b1 = (const float*)d_in[3];
    const float* W2 = (const float*)d_in[4];
    const float* b2 = (const float*)d_in[5];
    const float* Wd = (const float*)d_in[6];
    const float* bd = (const float*)d_in[7];
    int N = in_sizes[0] / 64;
    int E = in_sizes[1] / 2;
    const int* srcIdx = ei;
    const int* dstIdx = ei + E;
    int NB = (N + 255) >> BIN_SHIFT;  // coarse buckets

    char* w = (char*)d_ws;
    auto alloc = [&](size_t bytes) {
        void* p = (void*)w;
        w += (bytes + 255) & ~(size_t)255;
        return p;
    };
    int* counts = (int*)alloc((size_t)N * 4);
    int* offsets = (int*)alloc((size_t)(N + 1) * 4);
    int* ccounts = (int*)alloc((size_t)BIN_MAXB * 4);
    int* coff = (int*)alloc((size_t)(BIN_MAXB + 1) * 4);
    int* ccur = (int*)alloc((size_t)BIN_MAXB * 4);
    int* sorted_src = (int*)alloc((size_t)E * 4);
    float* dinv = (float*)alloc((size_t)N * 4);
    unsigned short* xsc = (unsigned short*)alloc((size_t)N * 64 * 2);
    unsigned short* gsc = (unsigned short*)alloc((size_t)N * 64 * 2);
    // fbf ALIASES xsc: xsc is dead after k_agg_bf<false>; fbf is first written
    // by k_agg_bf<true> two kernels later (same stream) -> no workspace growth.
    unsigned short* fbf = xsc;
    // z1 doubles as the pass-A pairs buffer (E*4 <= N*64*4 here); binfine
    // finishes before k_agg_bf<false> writes z1, same-stream ordering makes
    // the aliasing safe.
    size_t z1_bytes = (size_t)N * 64 * 4;
    size_t pairs_bytes = (size_t)E * 4;
    float* z1 = (float*)alloc(z1_bytes > pairs_bytes ? z1_bytes : pairs_bytes);
    unsigned int* pairs = (unsigned int*)z1;
    float* outLogp = (float*)d_out;
    float* outFinal = (float*)d_out + (size_t)N * 256;

    hipMemsetAsync(ccounts, 0, (size_t)BIN_MAXB * 4, stream);

    // coarse count -> scan -> bin -> per-bucket fine count/scan/scatter
    k_ccount<<<(E + BIN_CHUNK - 1) / BIN_CHUNK, 256, 0, stream>>>(dstIdx, E, ccounts);
    k_cscan<<<1, BIN_MAXB, 0, stream>>>(ccounts, NB, N, coff, ccur, offsets);
    k_binA<<<(E + BIN_CHUNK - 1) / BIN_CHUNK, 256, 0, stream>>>(srcIdx, dstIdx, E, ccur, pairs);
    k_binfine<<<NB, 256, 0, stream>>>(pairs, coff, N, counts, offsets, sorted_src);

    k_dinv<<<(N + 255) / 256, 256, 0, stream>>>(counts, N, dinv);
    k_prep<<<(N * 16 + 255) / 256, 256, 0, stream>>>(x, dinv, N, xsc);

    // layer 1: z1 = A_hat-weighted sum of xsc (already dinv-prescaled)
    k_agg_bf<false><<<(N + 3) / 4, 256, 0, stream>>>(xsc, dinv, offsets, sorted_src, nullptr, N, z1, nullptr);

    // fused MLP: gsc = bf16(dinv .* (relu(z1@W1+b1) @ W2))
    k_fused<<<(N + 31) / 32, 256, 0, stream>>>(z1, W1, b1, W2, dinv, N, gsc);

    // layer 2 aggregation + bias + row-normalize -> final embeddings (+bf16 copy into fbf=xsc)
    k_agg_bf<true><<<(N + 3) / 4, 256, 0, stream>>>(gsc, dinv, offsets, sorted_src, b2, N, outFinal, fbf);

    // decoder + log_softmax (MFMA, grid-stride over 16-row tasks)
    k_dec<<<1024, 256, 0, stream>>>(fbf, Wd, bd, N, outLogp);
}

// Round 11
// 421.172 us; speedup vs baseline: 1.2840x; 1.1474x over previous
//
#include <hip/hip_runtime.h>
#include <math.h>

#define BIN_SHIFT 8      // coarse bucket = dst >> 8 (256 nodes/bucket)
#define BIN_MAXB 512     // LDS array size (NB = ceil(N/256) = 391 for N=100000)
#define BIN_CHUNK 8192   // edges per block in coarse passes

typedef __attribute__((ext_vector_type(8))) short bf16x8;
typedef __attribute__((ext_vector_type(4))) float f32x4;

// ---- bf16 helpers (RNE) ----
__device__ __forceinline__ float bf2f(unsigned short u) {
    union { unsigned int i; float f; } v;
    v.i = ((unsigned int)u) << 16;
    return v.f;
}
__device__ __forceinline__ unsigned short f2bf(float f) {
    union { float f; unsigned int i; } v;
    v.f = f;
    unsigned int r = v.i + 0x7FFF + ((v.i >> 16) & 1);
    return (unsigned short)(r >> 16);
}
__device__ __forceinline__ float lo_bf(unsigned int u) {
    union { unsigned int i; float f; } v;
    v.i = u << 16;
    return v.f;
}
__device__ __forceinline__ float hi_bf(unsigned int u) {
    union { unsigned int i; float f; } v;
    v.i = u & 0xFFFF0000u;
    return v.f;
}

// ---------------- coarse bucket histogram (LDS-local, ~391 global atomics/block)
__global__ __launch_bounds__(256) void k_ccount(const int* __restrict__ dst, int E,
                                                int* __restrict__ ccounts) {
    __shared__ int hist[BIN_MAXB];
    int t = threadIdx.x;
    int e0 = blockIdx.x * BIN_CHUNK;
    int eEnd = e0 + BIN_CHUNK;
    if (eEnd > E) eEnd = E;
    for (int i = t; i < BIN_MAXB; i += 256) hist[i] = 0;
    __syncthreads();
    for (int e = e0 + t; e < eEnd; e += 256)
        atomicAdd(&hist[dst[e] >> BIN_SHIFT], 1);
    __syncthreads();
    for (int i = t; i < BIN_MAXB; i += 256) {
        int h = hist[i];
        if (h > 0) atomicAdd(&ccounts[i], h);
    }
}

// ---------------- single-block scan of coarse counts -> coff, ccur
__global__ void k_cscan(const int* __restrict__ ccounts, int NB, int N,
                        int* __restrict__ coff, int* __restrict__ ccur,
                        int* __restrict__ offsets) {
    __shared__ int s[BIN_MAXB];
    int t = threadIdx.x;
    int v = (t < NB) ? ccounts[t] : 0;
    s[t] = v;
    __syncthreads();
    for (int off = 1; off < BIN_MAXB; off <<= 1) {
        int tmp = (t >= off) ? s[t - off] : 0;
        __syncthreads();
        s[t] += tmp;
        __syncthreads();
    }
    int excl = s[t] - v;
    if (t < NB) {
        coff[t] = excl;
        ccur[t] = excl;
    }
    if (t == NB - 1) {
        coff[NB] = s[t];      // total = E
        offsets[N] = s[t];
    }
}

// ---------------- pass A: coarse-bin edges into pairs[] as (src<<8)|(dst&255)
__global__ __launch_bounds__(256) void k_binA(const int* __restrict__ src,
                                              const int* __restrict__ dst, int E,
                                              int* __restrict__ ccur,
                                              unsigned int* __restrict__ pairs) {
    __shared__ int hist[BIN_MAXB];
    __shared__ int base[BIN_MAXB];
    int t = threadIdx.x;
    int e0 = blockIdx.x * BIN_CHUNK;
    int eEnd = e0 + BIN_CHUNK;
    if (eEnd > E) eEnd = E;
    for (int i = t; i < BIN_MAXB; i += 256) hist[i] = 0;
    __syncthreads();
    for (int e = e0 + t; e < eEnd; e += 256) {
        int d = dst[e];
        atomicAdd(&hist[d >> BIN_SHIFT], 1);
    }
    __syncthreads();
    for (int i = t; i < BIN_MAXB; i += 256) {
        int h = hist[i];
        base[i] = (h > 0) ? atomicAdd(&ccur[i], h) : 0;
        hist[i] = 0;  // reuse as local cursor
    }
    __syncthreads();
    for (int e = e0 + t; e < eEnd; e += 256) {
        int d = dst[e];
        int s = src[e];
        int b = d >> BIN_SHIFT;
        int lp = atomicAdd(&hist[b], 1);
        pairs[base[b] + lp] = ((unsigned int)s << BIN_SHIFT) | (unsigned int)(d & 255);
    }
}

// ---------------- pass B (merged): per-bucket fine count + scan + scatter.
__global__ __launch_bounds__(256) void k_binfine(const unsigned int* __restrict__ pairs,
                                                 const int* __restrict__ coff,
                                                 int N,
                                                 int* __restrict__ counts,
                                                 int* __restrict__ offsets,
                                                 int* __restrict__ sorted_src) {
    __shared__ int hist[256];
    __shared__ int scan[256];
    __shared__ int lcur[256];
    int b = blockIdx.x;
    int t = threadIdx.x;
    int beg = coff[b], end = coff[b + 1];
    int dbase = b << BIN_SHIFT;
    hist[t] = 0;
    __syncthreads();
    for (int e = beg + t; e < end; e += 256)
        atomicAdd(&hist[pairs[e] & 255u], 1);
    __syncthreads();
    int v = hist[t];
    scan[t] = v;
    __syncthreads();
    for (int off = 1; off < 256; off <<= 1) {
        int tmp = (t >= off) ? scan[t - off] : 0;
        __syncthreads();
        scan[t] += tmp;
        __syncthreads();
    }
    int excl = scan[t] - v;
    int node = dbase + t;
    if (node < N) {
        counts[node] = v;              // non-atomic: this block owns these nodes
        offsets[node] = beg + excl;
    }
    lcur[t] = beg + excl;
    __syncthreads();
    for (int e = beg + t; e < end; e += 256) {
        unsigned int pk = pairs[e];
        int pos = atomicAdd(&lcur[pk & 255u], 1);   // LDS atomic
        sorted_src[pos] = (int)(pk >> BIN_SHIFT);
    }
}

__global__ void k_dinv(const int* __restrict__ counts, int N, float* __restrict__ dinv) {
    int i = blockIdx.x * blockDim.x + threadIdx.x;
    if (i < N) dinv[i] = rsqrtf((float)counts[i] + 1.0f);
}

// xsc[i][f] = bf16(dinv[i] * x[i][f]); one thread per float4
__global__ void k_prep(const float* __restrict__ x, const float* __restrict__ dinv,
                       int N, unsigned short* __restrict__ xsc) {
    int i = blockIdx.x * blockDim.x + threadIdx.x;  // over N*16 float4s
    if (i >= N * 16) return;
    int node = i >> 4;
    float d = dinv[node];
    float4 v = ((const float4*)x)[i];
    ushort4 u;
    u.x = f2bf(v.x * d);
    u.y = f2bf(v.y * d);
    u.z = f2bf(v.z * d);
    u.w = f2bf(v.w * d);
    ((ushort4*)xsc)[i] = u;
}

// ---------------- aggregation over bf16, dinv-prescaled features
// Wave layout: g = lane>>3 picks one of 8 edges/iter, c = lane&7 picks an
// 8-feature octet (uint4 = 16 B). One gather instr covers 8 edge rows.
// !FINAL: g==0 lanes write bf16 z1 (MFMA MLP input).
// FINAL:  g==0 lanes write fp32 embeddings, g==1 lanes write bf16 copy.
template <bool FINAL>
__global__ __launch_bounds__(256) void k_agg_bf(const unsigned short* __restrict__ fsc,
                                                const float* __restrict__ dinv,
                                                const int* __restrict__ offsets,
                                                const int* __restrict__ sorted_src,
                                                const float* __restrict__ b2,
                                                int N, float* __restrict__ out,
                                                unsigned short* __restrict__ outbf) {
    int wid = threadIdx.x >> 6;
    int lane = threadIdx.x & 63;
    int g = lane >> 3;   // edge slot 0..7
    int c = lane & 7;    // feature octet
    int i = blockIdx.x * 4 + wid;
    if (i >= N) return;
    int beg = offsets[i], end = offsets[i + 1];
    const unsigned short* fsc_c = fsc + (c << 3);

    float a0 = 0.f, a1 = 0.f, a2 = 0.f, a3 = 0.f;
    float a4 = 0.f, a5 = 0.f, a6 = 0.f, a7 = 0.f;

    int e = beg;
    // 2x unrolled: 16 edges per body, two independent gathers in flight
    for (; e + 15 < end; e += 16) {
        int s0 = sorted_src[e + g];
        int s1 = sorted_src[e + 8 + g];
        uint4 v0 = *(const uint4*)(fsc_c + ((unsigned)s0 << 6));
        uint4 v1 = *(const uint4*)(fsc_c + ((unsigned)s1 << 6));
        a0 += lo_bf(v0.x); a1 += hi_bf(v0.x);
        a2 += lo_bf(v0.y); a3 += hi_bf(v0.y);
        a4 += lo_bf(v0.z); a5 += hi_bf(v0.z);
        a6 += lo_bf(v0.w); a7 += hi_bf(v0.w);
        a0 += lo_bf(v1.x); a1 += hi_bf(v1.x);
        a2 += lo_bf(v1.y); a3 += hi_bf(v1.y);
        a4 += lo_bf(v1.z); a5 += hi_bf(v1.z);
        a6 += lo_bf(v1.w); a7 += hi_bf(v1.w);
    }
    for (; e + 7 < end; e += 8) {
        int s0 = sorted_src[e + g];
        uint4 v0 = *(const uint4*)(fsc_c + ((unsigned)s0 << 6));
        a0 += lo_bf(v0.x); a1 += hi_bf(v0.x);
        a2 += lo_bf(v0.y); a3 += hi_bf(v0.y);
        a4 += lo_bf(v0.z); a5 += hi_bf(v0.z);
        a6 += lo_bf(v0.w); a7 += hi_bf(v0.w);
    }
    int rem = end - e;
    if (rem > 0) {
        int idx = e + ((g < rem) ? g : 0);
        int s0 = sorted_src[idx];
        uint4 v0 = *(const uint4*)(fsc_c + ((unsigned)s0 << 6));
        if (g < rem) {
            a0 += lo_bf(v0.x); a1 += hi_bf(v0.x);
            a2 += lo_bf(v0.y); a3 += hi_bf(v0.y);
            a4 += lo_bf(v0.z); a5 += hi_bf(v0.z);
            a6 += lo_bf(v0.w); a7 += hi_bf(v0.w);
        }
    }
    // reduce across the 8 edge groups (lane bits 3,4,5)
#pragma unroll
    for (int m = 8; m <= 32; m <<= 1) {
        a0 += __shfl_xor(a0, m, 64);
        a1 += __shfl_xor(a1, m, 64);
        a2 += __shfl_xor(a2, m, 64);
        a3 += __shfl_xor(a3, m, 64);
        a4 += __shfl_xor(a4, m, 64);
        a5 += __shfl_xor(a5, m, 64);
        a6 += __shfl_xor(a6, m, 64);
        a7 += __shfl_xor(a7, m, 64);
    }
    // self-loop term (already dinv-scaled); identical on all lanes of a group
    {
        uint4 v = *(const uint4*)(fsc_c + ((unsigned)i << 6));
        a0 += lo_bf(v.x); a1 += hi_bf(v.x);
        a2 += lo_bf(v.y); a3 += hi_bf(v.y);
        a4 += lo_bf(v.z); a5 += hi_bf(v.z);
        a6 += lo_bf(v.w); a7 += hi_bf(v.w);
    }
    float di = dinv[i];
    if (!FINAL) {
        if (g == 0) {
            uint4 pk;
            pk.x = (unsigned)f2bf(a0 * di) | ((unsigned)f2bf(a1 * di) << 16);
            pk.y = (unsigned)f2bf(a2 * di) | ((unsigned)f2bf(a3 * di) << 16);
            pk.z = (unsigned)f2bf(a4 * di) | ((unsigned)f2bf(a5 * di) << 16);
            pk.w = (unsigned)f2bf(a6 * di) | ((unsigned)f2bf(a7 * di) << 16);
            *(uint4*)(outbf + (size_t)i * 64 + (c << 3)) = pk;
        }
    } else {
        const float* bp = b2 + (c << 3);
        float4 bA = *(const float4*)(bp + 0);
        float4 bB = *(const float4*)(bp + 4);
        float z0 = a0 * di + bA.x;
        float z1 = a1 * di + bA.y;
        float z2 = a2 * di + bA.z;
        float z3 = a3 * di + bA.w;
        float z4 = a4 * di + bB.x;
        float z5 = a5 * di + bB.y;
        float z6 = a6 * di + bB.z;
        float z7 = a7 * di + bB.w;
        float sq = z0 * z0 + z1 * z1 + z2 * z2 + z3 * z3 +
                   z4 * z4 + z5 * z5 + z6 * z6 + z7 * z7;
#pragma unroll
        for (int m = 1; m <= 4; m <<= 1) sq += __shfl_xor(sq, m, 64);
        float r = 1.0f / (sqrtf(sq) + 1e-12f);
        if (g == 0) {
            float* op = out + (size_t)i * 64 + (c << 3);
            *(float4*)(op + 0) = make_float4(z0 * r, z1 * r, z2 * r, z3 * r);
            *(float4*)(op + 4) = make_float4(z4 * r, z5 * r, z6 * r, z7 * r);
        } else if (g == 1) {
            uint4 pk;
            pk.x = (unsigned)f2bf(z0 * r) | ((unsigned)f2bf(z1 * r) << 16);
            pk.y = (unsigned)f2bf(z2 * r) | ((unsigned)f2bf(z3 * r) << 16);
            pk.z = (unsigned)f2bf(z4 * r) | ((unsigned)f2bf(z5 * r) << 16);
            pk.w = (unsigned)f2bf(z6 * r) | ((unsigned)f2bf(z7 * r) << 16);
            *(uint4*)(outbf + (size_t)i * 64 + (c << 3)) = pk;
        }
    }
}

// ---------------- fused MLP via MFMA (swapped operands):
// H^T = W1^T @ z1^T; G^T = W2^T @ H^T; gsc = bf16(dinv .* G).
// Weights live in registers as A-fragments (loaded once per block, L2-hot).
// Per wave, per 16-node task: 2 z1 loads + 16 MFMA + LDS transpose (wave-
// private Hlds[node][hcol]) + 16 MFMA + 4 gsc writes. No barriers.
// Frag layouts (validated by k_dec pass): A row=lane&15,k=(lane>>4)*8+j;
// B col=lane&15, same k; D col=lane&15,row=(lane>>4)*4+r.
__global__ __launch_bounds__(256, 2) void k_fused(const unsigned short* __restrict__ z1bf,
                                                  const float* __restrict__ W1,
                                                  const float* __restrict__ b1,
                                                  const float* __restrict__ W2,
                                                  const float* __restrict__ dinv,
                                                  int N, unsigned short* __restrict__ gsc) {
    __shared__ unsigned short Hlds[4][16][136];  // pad 128->136: 16B-aligned rows, ~2-way banks
    int t = threadIdx.x;
    int w = t >> 6, lane = t & 63;
    int l15 = lane & 15, lhi = lane >> 4;

    // A-frags of W1^T: A1f[ct][kh][j] = W1[kh*32+lhi*8+j][ct*16+l15]
    bf16x8 A1f[8][2];
#pragma unroll
    for (int ct = 0; ct < 8; ct++)
#pragma unroll
        for (int kh = 0; kh < 2; kh++) {
            bf16x8 f;
#pragma unroll
            for (int j = 0; j < 8; j++)
                f[j] = (short)f2bf(W1[(kh * 32 + lhi * 8 + j) * 128 + ct * 16 + l15]);
            A1f[ct][kh] = f;
        }
    // A-frags of W2^T: A2f[ct2][kh2][j] = W2[kh2*32+lhi*8+j][ct2*16+l15]
    bf16x8 A2f[4][4];
#pragma unroll
    for (int ct2 = 0; ct2 < 4; ct2++)
#pragma unroll
        for (int kh2 = 0; kh2 < 4; kh2++) {
            bf16x8 f;
#pragma unroll
            for (int j = 0; j < 8; j++)
                f[j] = (short)f2bf(W2[(kh2 * 32 + lhi * 8 + j) * 64 + ct2 * 16 + l15]);
            A2f[ct2][kh2] = f;
        }
    // bias for this lane's held hcols: b1v[ct][r] = b1[ct*16+lhi*4+r]
    float b1v[8][4];
#pragma unroll
    for (int ct = 0; ct < 8; ct++) {
        float4 bv = *(const float4*)&b1[ct * 16 + lhi * 4];
        b1v[ct][0] = bv.x; b1v[ct][1] = bv.y; b1v[ct][2] = bv.z; b1v[ct][3] = bv.w;
    }

    int nTasks = (N + 15) / 16;
    for (int task = blockIdx.x * 4 + w; task < nTasks; task += gridDim.x * 4) {
        int r0 = task * 16;
        int node = r0 + l15;
        bf16x8 Bz0 = {};
        bf16x8 Bz1 = {};
        if (node < N) {
            Bz0 = *(const bf16x8*)(z1bf + (size_t)node * 64 + lhi * 8);
            Bz1 = *(const bf16x8*)(z1bf + (size_t)node * 64 + 32 + lhi * 8);
        }
        // stage 1: per col-tile ct, D1[row=hcol-in-tile][col=node]
#pragma unroll
        for (int ct = 0; ct < 8; ct++) {
            f32x4 acc = {0.f, 0.f, 0.f, 0.f};
            acc = __builtin_amdgcn_mfma_f32_16x16x32_bf16(A1f[ct][0], Bz0, acc, 0, 0, 0);
            acc = __builtin_amdgcn_mfma_f32_16x16x32_bf16(A1f[ct][1], Bz1, acc, 0, 0, 0);
            ushort4 hu;
            hu.x = f2bf(fmaxf(acc[0] + b1v[ct][0], 0.f));
            hu.y = f2bf(fmaxf(acc[1] + b1v[ct][1], 0.f));
            hu.z = f2bf(fmaxf(acc[2] + b1v[ct][2], 0.f));
            hu.w = f2bf(fmaxf(acc[3] + b1v[ct][3], 0.f));
            *(ushort4*)&Hlds[w][l15][ct * 16 + lhi * 4] = hu;  // H[node l15][hcol..+4]
        }
        // stage 2 B-frags: Bh[kh2] = H[node l15][kh2*32+lhi*8 .. +8] (wave-private)
        bf16x8 Bh[4];
#pragma unroll
        for (int kh2 = 0; kh2 < 4; kh2++)
            Bh[kh2] = *(const bf16x8*)&Hlds[w][l15][kh2 * 32 + lhi * 8];
        float di = (node < N) ? dinv[node] : 0.f;
#pragma unroll
        for (int ct2 = 0; ct2 < 4; ct2++) {
            f32x4 acc = {0.f, 0.f, 0.f, 0.f};
            acc = __builtin_amdgcn_mfma_f32_16x16x32_bf16(A2f[ct2][0], Bh[0], acc, 0, 0, 0);
            acc = __builtin_amdgcn_mfma_f32_16x16x32_bf16(A2f[ct2][1], Bh[1], acc, 0, 0, 0);
            acc = __builtin_amdgcn_mfma_f32_16x16x32_bf16(A2f[ct2][2], Bh[2], acc, 0, 0, 0);
            acc = __builtin_amdgcn_mfma_f32_16x16x32_bf16(A2f[ct2][3], Bh[3], acc, 0, 0, 0);
            if (node < N) {
                ushort4 o;
                o.x = f2bf(acc[0] * di);
                o.y = f2bf(acc[1] * di);
                o.z = f2bf(acc[2] * di);
                o.w = f2bf(acc[3] * di);
                *(ushort4*)(gsc + (size_t)node * 64 + ct2 * 16 + lhi * 4) = o;
            }
        }
    }
}

// ---------------- decoder GEMM (64->256) via MFMA, fused log_softmax
__global__ __launch_bounds__(256, 2) void k_dec(const unsigned short* __restrict__ Fbf,
                                                const float* __restrict__ Wd,
                                                const float* __restrict__ bd,
                                                int N, float* __restrict__ out) {
    __shared__ float redM[4][16];
    __shared__ float redS[4][16];
    int t = threadIdx.x;
    int w = t >> 6, lane = t & 63;
    int l15 = lane & 15, lhi = lane >> 4;
    int cbase = w * 64;

    // B fragments + bias, once per block
    bf16x8 B[4][2];
    float bb[4];
#pragma unroll
    for (int c = 0; c < 4; c++) {
        int col = cbase + c * 16 + l15;
        bb[c] = bd[col];
#pragma unroll
        for (int kh = 0; kh < 2; kh++) {
            bf16x8 bf;
#pragma unroll
            for (int j = 0; j < 8; j++) {
                int k = kh * 32 + lhi * 8 + j;
                bf[j] = (short)f2bf(Wd[k * 256 + col]);
            }
            B[c][kh] = bf;
        }
    }

    int nTasks = (N + 15) / 16;
    for (int task = blockIdx.x; task < nTasks; task += gridDim.x) {
        int r0 = task * 16;
        int rowA = r0 + l15;
        bf16x8 A0 = {};
        bf16x8 A1 = {};
        if (rowA < N) {
            A0 = *(const bf16x8*)(Fbf + (size_t)rowA * 64 + lhi * 8);
            A1 = *(const bf16x8*)(Fbf + (size_t)rowA * 64 + 32 + lhi * 8);
        }
        float z[4][4];  // [col-tile][r]
#pragma unroll
        for (int c = 0; c < 4; c++) {
            f32x4 acc = {0.f, 0.f, 0.f, 0.f};
            acc = __builtin_amdgcn_mfma_f32_16x16x32_bf16(A0, B[c][0], acc, 0, 0, 0);
            acc = __builtin_amdgcn_mfma_f32_16x16x32_bf16(A1, B[c][1], acc, 0, 0, 0);
#pragma unroll
            for (int r = 0; r < 4; r++) z[c][r] = acc[r] + bb[c];
        }
        // per-row max over this wave's 64 cols
        float M[4];
#pragma unroll
        for (int r = 0; r < 4; r++) {
            float m = fmaxf(fmaxf(z[0][r], z[1][r]), fmaxf(z[2][r], z[3][r]));
#pragma unroll
            for (int mm = 1; mm <= 8; mm <<= 1) m = fmaxf(m, __shfl_xor(m, mm, 64));
            M[r] = m;
        }
        if (l15 == 0) {
#pragma unroll
            for (int r = 0; r < 4; r++) redM[w][lhi * 4 + r] = M[r];
        }
        __syncthreads();
        float sr[4];
#pragma unroll
        for (int r = 0; r < 4; r++) {
            int rl = lhi * 4 + r;
            M[r] = fmaxf(fmaxf(redM[0][rl], redM[1][rl]), fmaxf(redM[2][rl], redM[3][rl]));
            float s = __expf(z[0][r] - M[r]) + __expf(z[1][r] - M[r]) +
                      __expf(z[2][r] - M[r]) + __expf(z[3][r] - M[r]);
#pragma unroll
            for (int mm = 1; mm <= 8; mm <<= 1) s += __shfl_xor(s, mm, 64);
            sr[r] = s;
        }
        if (l15 == 0) {
#pragma unroll
            for (int r = 0; r < 4; r++) redS[w][lhi * 4 + r] = sr[r];
        }
        __syncthreads();
#pragma unroll
        for (int r = 0; r < 4; r++) {
            int rl = lhi * 4 + r;
            int grow = r0 + rl;
            if (grow < N) {
                float s = redS[0][rl] + redS[1][rl] + redS[2][rl] + redS[3][rl];
                float lz = M[r] + __logf(s);
#pragma unroll
                for (int c = 0; c < 4; c++)
                    out[(size_t)grow * 256 + cbase + c * 16 + l15] = z[c][r] - lz;
            }
        }
        __syncthreads();  // protect redM/redS before next iteration's writes
    }
}

extern "C" void kernel_launch(void* const* d_in, const int* in_sizes, int n_in,
                              void* d_out, int out_size, void* d_ws, size_t ws_size,
                              hipStream_t stream) {
    const float* x = (const float*)d_in[0];
    const int* ei = (const int*)d_in[1];
    const float* W1 = (const float*)d_in[2];
    const float* b1 = (const float*)d_in[3];
    const float* W2 = (const float*)d_in[4];
    const float* b2 = (const float*)d_in[5];
    const float* Wd = (const float*)d_in[6];
    const float* bd = (const float*)d_in[7];
    int N = in_sizes[0] / 64;
    int E = in_sizes[1] / 2;
    const int* srcIdx = ei;
    const int* dstIdx = ei + E;
    int NB = (N + 255) >> BIN_SHIFT;  // coarse buckets

    char* w = (char*)d_ws;
    auto alloc = [&](size_t bytes) {
        void* p = (void*)w;
        w += (bytes + 255) & ~(size_t)255;
        return p;
    };
    int* counts = (int*)alloc((size_t)N * 4);
    int* offsets = (int*)alloc((size_t)(N + 1) * 4);
    int* ccounts = (int*)alloc((size_t)BIN_MAXB * 4);
    int* coff = (int*)alloc((size_t)(BIN_MAXB + 1) * 4);
    int* ccur = (int*)alloc((size_t)BIN_MAXB * 4);
    int* sorted_src = (int*)alloc((size_t)E * 4);
    float* dinv = (float*)alloc((size_t)N * 4);
    unsigned short* xsc = (unsigned short*)alloc((size_t)N * 64 * 2);
    unsigned short* gsc = (unsigned short*)alloc((size_t)N * 64 * 2);
    // fbf ALIASES xsc: xsc dead after k_agg_bf<false>; fbf first written by
    // k_agg_bf<true> (same stream) -> no workspace growth.
    unsigned short* fbf = xsc;
    // z1bf (bf16 MLP input) aliases the pass-A pairs buffer: pairs dead after
    // k_binfine; z1bf written by k_agg_bf<false> afterwards.
    size_t z1_bytes = (size_t)N * 64 * 2;
    size_t pairs_bytes = (size_t)E * 4;
    unsigned short* z1bf = (unsigned short*)alloc(z1_bytes > pairs_bytes ? z1_bytes : pairs_bytes);
    unsigned int* pairs = (unsigned int*)z1bf;
    float* outLogp = (float*)d_out;
    float* outFinal = (float*)d_out + (size_t)N * 256;

    hipMemsetAsync(ccounts, 0, (size_t)BIN_MAXB * 4, stream);

    // coarse count -> scan -> bin -> per-bucket fine count/scan/scatter
    k_ccount<<<(E + BIN_CHUNK - 1) / BIN_CHUNK, 256, 0, stream>>>(dstIdx, E, ccounts);
    k_cscan<<<1, BIN_MAXB, 0, stream>>>(ccounts, NB, N, coff, ccur, offsets);
    k_binA<<<(E + BIN_CHUNK - 1) / BIN_CHUNK, 256, 0, stream>>>(srcIdx, dstIdx, E, ccur, pairs);
    k_binfine<<<NB, 256, 0, stream>>>(pairs, coff, N, counts, offsets, sorted_src);

    k_dinv<<<(N + 255) / 256, 256, 0, stream>>>(counts, N, dinv);
    k_prep<<<(N * 16 + 255) / 256, 256, 0, stream>>>(x, dinv, N, xsc);

    // layer 1: z1bf = bf16(A_hat-weighted sum of xsc)
    k_agg_bf<false><<<(N + 3) / 4, 256, 0, stream>>>(xsc, dinv, offsets, sorted_src, nullptr, N, nullptr, z1bf);

    // fused MLP via MFMA: gsc = bf16(dinv .* (relu(z1@W1+b1) @ W2))
    k_fused<<<512, 256, 0, stream>>>(z1bf, W1, b1, W2, dinv, N, gsc);

    // layer 2 aggregation + bias + row-normalize -> final embeddings (+bf16 copy into fbf=xsc)
    k_agg_bf<true><<<(N + 3) / 4, 256, 0, stream>>>(gsc, dinv, offsets, sorted_src, b2, N, outFinal, fbf);

    // decoder + log_softmax (MFMA, grid-stride over 16-row tasks)
    k_dec<<<1024, 256, 0, stream>>>(fbf, Wd, bd, N, outLogp);
}